// Round 10
// baseline (82.861 us; speedup 1.0000x reference)
//
#include <hip/hip_runtime.h>
#include <hip/hip_bf16.h>
#include <stdint.h>
#include <math.h>

#define B_N 128
#define D_N 512
#define H_N 1024
#define C_N 1000
#define CP  1024                 // padded row stride for logit partials / g
#define NJT 16                   // j-split planes (K=64 each) -- absmax-0-proven order
#define LP_STRIDE (B_N * CP)

// ---------------------------------------------------------------------------
// threefry2x32 (JAX-compatible, 20 rounds) -- verified bit-exact (R1 absmax 0)
// ---------------------------------------------------------------------------
__device__ __forceinline__ uint32_t rotl32(uint32_t v, int r) {
  return (v << r) | (v >> (32 - r));
}

__device__ __forceinline__ void threefry2x32(uint32_t k0, uint32_t k1,
                                             uint32_t x0, uint32_t x1,
                                             uint32_t &o0, uint32_t &o1) {
  uint32_t ks2 = k0 ^ k1 ^ 0x1BD11BDAu;
#define TF_R(r) { x0 += x1; x1 = rotl32(x1, r); x1 ^= x0; }
  x0 += k0; x1 += k1;
  TF_R(13) TF_R(15) TF_R(26) TF_R(6)
  x0 += k1; x1 += ks2 + 1u;
  TF_R(17) TF_R(29) TF_R(16) TF_R(24)
  x0 += ks2; x1 += k0 + 2u;
  TF_R(13) TF_R(15) TF_R(26) TF_R(6)
  x0 += k0; x1 += k1 + 3u;
  TF_R(17) TF_R(29) TF_R(16) TF_R(24)
  x0 += k1; x1 += ks2 + 4u;
  TF_R(13) TF_R(15) TF_R(26) TF_R(6)
  x0 += ks2; x1 += k0 + 5u;
#undef TF_R
  o0 = x0; o1 = x1;
}

__device__ __forceinline__ float gumbel_from_key(uint32_t k0, uint32_t k1, uint32_t i) {
  uint32_t o0, o1;
  threefry2x32(k0, k1, 0u, i, o0, o1);
  uint32_t bits = o0 ^ o1;
  uint32_t fb = (bits >> 9) | 0x3f800000u;
  float f = __uint_as_float(fb) - 1.0f;            // [0, 1)
  const float tiny = 1.1754943508222875e-38f;
  float u = fmaxf(tiny, f * (1.0f - tiny) + tiny); // JAX uniform(minval=tiny)
  return -logf(-logf(u));
}

// ---------------------------------------------------------------------------
__device__ __forceinline__ float wave_sum(float v) {
  #pragma unroll
  for (int o = 32; o; o >>= 1) v += __shfl_xor(v, o);
  return v;
}

__device__ __forceinline__ float block_sum512(float v, float* red) {
  #pragma unroll
  for (int o = 32; o; o >>= 1) v += __shfl_xor(v, o);
  __syncthreads();
  if ((threadIdx.x & 63) == 0) red[threadIdx.x >> 6] = v;
  __syncthreads();
  return red[0] + red[1] + red[2] + red[3] + red[4] + red[5] + red[6] + red[7];
}

// ---------------------------------------------------------------------------
// NODE 1: fused fc1+fc2 per j-slab. grid 256 = sg(16: 8 samples) x jt(16: 64 j).
// bid = sg*16 + jt -> XCD = jt%8 (W1 slab 128 KB + W2 slab 256 KB L2-resident,
// shared by the 16 sg-blocks of each jt).
// Phase A: h[8s][64j] = X @ W1[:,slab] + b1, K=512 ascending (bit-identical to
//          R9 fc1); write hfinal; relu -> LDS hT. Also: gumbel table (gumbel is
//          logit-independent), xsq (jt==0), counter reset (bid==0).
// Phase B: lpart[jt] = relu(h) @ W2[slab,:], j ascending (bit-identical to R9
//          fc2). Pads [1000,1024) unwritten; consumers guard c < C_N.
// ---------------------------------------------------------------------------
__global__ __launch_bounds__(512) void k_fwd(const float* __restrict__ X,
                                             const float* __restrict__ W1,
                                             const float* __restrict__ b1,
                                             const float* __restrict__ W2,
                                             float* __restrict__ hfinal,
                                             float* __restrict__ lpart,
                                             float* __restrict__ gtab,
                                             float* __restrict__ xsq,
                                             unsigned int* __restrict__ counter) {
  __shared__ float xs[8 * D_N];   // 16 KB [s][d]
  __shared__ float hT[64 * 9];    // [j][s], pad 9 to spread banks
  int bid = blockIdx.x;
  int sg = bid >> 4, jt = bid & 15;
  int sbase = sg * 8, jbase = jt * 64;
  int t = threadIdx.x;
  if (bid == 0 && t == 0) *counter = 0u;

  #pragma unroll
  for (int k = 0; k < 2; k++) {
    int i4 = t + k * 512;          // 0..1023 float4s = 8 rows x 128
    int s = i4 >> 7, dq = i4 & 127;
    *reinterpret_cast<float4*>(&xs[s * D_N + dq * 4]) =
        *reinterpret_cast<const float4*>(&X[(size_t)(sbase + s) * D_N + dq * 4]);
  }

  // gumbel table: gid -> (b, c); independent of logits, bit-same values as R9.
  {
    int gid = bid * 512 + t;       // 0..131071 = 128 x 1024 exactly
    int b = gid >> 10, c = gid & 1023;
    float gv = 0.f;
    if (c < C_N) {
      uint32_t o0, o1;
      threefry2x32(0u, 42u, 0u, (uint32_t)b, o0, o1);
      gv = gumbel_from_key(o0, o1, (uint32_t)c);
    }
    gtab[gid] = gv;
  }
  __syncthreads();

  // Phase A: fc1. thread = (s = t>>6, j = t&63); K = 512 ascending scalar adds.
  int s = t >> 6, j = t & 63;
  const float* W1c = W1 + jbase + j;
  const float* xp = &xs[s * D_N];
  float a0 = 0.f;
  float wA[8], wB[8];
  #pragma unroll
  for (int i = 0; i < 8; i++) wA[i] = W1c[(size_t)i * H_N];
  for (int d0 = 0; d0 < D_N; d0 += 16) {
    #pragma unroll
    for (int i = 0; i < 8; i++) wB[i] = W1c[(size_t)((d0 + 8 + i) & (D_N - 1)) * H_N];
    #pragma unroll
    for (int i = 0; i < 8; i++) a0 += wA[i] * xp[d0 + i];
    #pragma unroll
    for (int i = 0; i < 8; i++) wA[i] = W1c[(size_t)((d0 + 16 + i) & (D_N - 1)) * H_N];
    #pragma unroll
    for (int i = 0; i < 8; i++) a0 += wB[i] * xp[d0 + 8 + i];
  }
  float h = a0 + b1[jbase + j];
  hfinal[(size_t)(sbase + s) * H_N + jbase + j] = h;
  hT[j * 9 + s] = fmaxf(h, 0.f);

  if (jt == 0) {                   // xsq, same per-lane order as R9 (bit-exact)
    int lane = t & 63;
    float v = 0.f;
    #pragma unroll
    for (int k = 0; k < 8; k++) { float xv = xs[s * D_N + lane + k * 64]; v += xv * xv; }
    v = wave_sum(v);
    if (lane == 0) xsq[sbase + s] = v;
  }
  __syncthreads();

  // Phase B: fc2. thread = 2 c-cols (t, t+512) x 8 samples; j ascending 0..63.
  int c0 = t;
  bool c1ok = (t + 512) < C_N;
  float acc0[8] = {0,0,0,0,0,0,0,0};
  float acc1[8] = {0,0,0,0,0,0,0,0};
  const float* W2r = W2 + (size_t)jbase * C_N;
  #pragma unroll 8
  for (int jj = 0; jj < 64; jj++) {
    float w0 = W2r[(size_t)jj * C_N + c0];
    float w1 = c1ok ? W2r[(size_t)jj * C_N + c0 + 512] : 0.f;
    #pragma unroll
    for (int ss = 0; ss < 8; ss++) {
      float hv = hT[jj * 9 + ss];
      acc0[ss] += w0 * hv;
      acc1[ss] += w1 * hv;
    }
  }
  float* lp = lpart + (size_t)jt * LP_STRIDE;
  #pragma unroll
  for (int ss = 0; ss < 8; ss++) {
    lp[(size_t)(sbase + ss) * CP + c0] = acc0[ss];
    if (c1ok) lp[(size_t)(sbase + ss) * CP + c0 + 512] = acc1[ss];
  }
}

// ---------------------------------------------------------------------------
// NODE 2: fused sample+bwd. grid 256; 2D XCD tiling: xcd = (sg%4)*2 + (jt%2)
// -> per-XCD working set = 4 sgs' lpart rows (2 MB) + 8 jts' W2 (2 MB): L2.
// Wave w samples S = sg*8+w fully in-wave (R7-proven, bit-deterministic across
// the 16 redundant jt-blocks); g stays in LDS. Then R9-proven bwd slice for
// 64 j-rows, and R7/R9-proven arrival-counter final reduce (no spinning).
// ---------------------------------------------------------------------------
__global__ __launch_bounds__(512) void k_tail(const float* __restrict__ lpart,
                                              const float* __restrict__ b2,
                                              const float* __restrict__ gtab,
                                              const float* __restrict__ W2,
                                              const float* __restrict__ hfinal,
                                              const float* __restrict__ xsq_g,
                                              float* __restrict__ samp_part,
                                              float* __restrict__ bwd_part,
                                              unsigned int* __restrict__ counter,
                                              float* __restrict__ out) {
  __shared__ float lg[8 * 1024];   // g for 8 samples, pads zero
  __shared__ float tnormS[8], hsqS[8], xq[8];
  __shared__ float wred[8][2];
  __shared__ float red[8];
  __shared__ int isLast;
  int bid = blockIdx.x;
  int xcd = bid & 7, q = bid >> 3;
  int sg = ((q & 3) << 2) | (xcd >> 1);   // 16 sgs; sg%4 = xcd/2
  int jt = ((q >> 2) << 1) | (xcd & 1);   // 16 jts; jt%2 = xcd%2
  int sbase = sg * 8, jbase = jt * 64;
  int t = threadIdx.x, w = t >> 6, lane = t & 63;
  int S = sbase + w;

  // --- sampling (wave-local; b2-first then p=0..15 ascending = R9's exact
  //     per-element order -> bit-identical logits) ---
  float v[16];
  float bz = -INFINITY; int bi = 0x7fffffff;
  #pragma unroll
  for (int k = 0; k < 16; k++) {
    int c = lane + k * 64;
    float val = -INFINITY;
    if (c < C_N) {
      val = b2[c];
      #pragma unroll
      for (int p = 0; p < NJT; p++)
        val += lpart[(size_t)p * LP_STRIDE + (size_t)S * CP + c];
      float z = val + gtab[(size_t)S * CP + c];
      if (z > bz || (z == bz && c < bi)) { bz = z; bi = c; }
    }
    v[k] = val;
  }
  #pragma unroll
  for (int o = 32; o; o >>= 1) {
    float ov = __shfl_xor(bz, o); int oi = __shfl_xor(bi, o);
    if (ov > bz || (ov == bz && oi < bi)) { bz = ov; bi = oi; }
  }
  int y = bi;
  float m = v[0];
  #pragma unroll
  for (int k = 1; k < 16; k++) m = fmaxf(m, v[k]);
  #pragma unroll
  for (int o = 32; o; o >>= 1) m = fmaxf(m, __shfl_xor(m, o));
  float sum = 0.f;
  #pragma unroll
  for (int k = 0; k < 16; k++) { v[k] = expf(v[k] - m); sum += v[k]; }
  sum = wave_sum(sum);
  float inv = 1.0f / sum;
  float tn = 0.f;
  #pragma unroll
  for (int k = 0; k < 16; k++) {
    int c = lane + k * 64;
    float gv = v[k] * inv - ((c == y) ? 1.0f : 0.0f);
    if (c >= C_N) gv = 0.f;        // pads exactly zero
    lg[w * 1024 + c] = gv;
    tn += gv * gv;
  }
  tn = wave_sum(tn);
  if (lane == 0) tnormS[w] = tn;
  if (t < 8) xq[t] = xsq_g[sbase + t];
  if (jt == 0) {                   // ||relu(h)||^2 per sample (R7-proven)
    float hv = 0.f;
    #pragma unroll
    for (int k = 0; k < 16; k++) {
      float hh = hfinal[(size_t)S * H_N + lane + k * 64];
      float r = fmaxf(hh, 0.f);
      hv += r * r;
    }
    hv = wave_sum(hv);
    if (lane == 0) hsqS[w] = hv;
  }
  __syncthreads();

  // --- backward: 64 j-rows x 8 samples (R9 inner verbatim, gs := lg) ---
  float cb = 0.f, cw = 0.f;
  for (int it2 = 0; it2 < 4; it2++) {
    int jb = jbase + it2 * 16;
    int j0 = jb + w * 2, j1 = j0 + 1;
    float a0[8] = {0,0,0,0,0,0,0,0};
    float a1[8] = {0,0,0,0,0,0,0,0};
    const float* w2r0 = W2 + (size_t)j0 * C_N;
    const float* w2r1 = W2 + (size_t)j1 * C_N;
    #pragma unroll
    for (int it = 0; it < 4; it++) {
      int c0 = it * 256 + lane * 4;
      bool act = (c0 < C_N);       // W2 rows are 1000 wide: guard OOB
      float4 wv0 = act ? *reinterpret_cast<const float4*>(w2r0 + c0)
                       : make_float4(0.f, 0.f, 0.f, 0.f);
      float4 wv1 = act ? *reinterpret_cast<const float4*>(w2r1 + c0)
                       : make_float4(0.f, 0.f, 0.f, 0.f);
      #pragma unroll
      for (int s = 0; s < 8; s++) {
        float4 gv = *reinterpret_cast<const float4*>(&lg[s * 1024 + c0]);
        a0[s] += wv0.x * gv.x + wv0.y * gv.y + wv0.z * gv.z + wv0.w * gv.w;
        a1[s] += wv1.x * gv.x + wv1.y * gv.y + wv1.z * gv.z + wv1.w * gv.w;
      }
    }
    #pragma unroll
    for (int off = 32; off; off >>= 1) {
      #pragma unroll
      for (int s = 0; s < 8; s++) {
        a0[s] += __shfl_xor(a0[s], off);
        a1[s] += __shfl_xor(a1[s], off);
      }
    }
    #pragma unroll
    for (int s = 0; s < 8; s++) {
      float h0 = hfinal[(size_t)(sbase + s) * H_N + j0];
      float h1 = hfinal[(size_t)(sbase + s) * H_N + j1];
      float v0 = (h0 > 0.f) ? a0[s] : 0.f;
      float v1 = (h1 > 0.f) ? a1[s] : 0.f;
      float qq = v0 * v0 + v1 * v1;
      cb += qq;
      cw += xq[s] * qq;
    }
  }
  if (lane == 0) { wred[w][0] = cw; wred[w][1] = cb; }
  __syncthreads();

  // --- partial write, arrive, last-arriver final reduce ---
  if (t == 0) {
    float sw = 0.f, sb = 0.f;
    #pragma unroll
    for (int i = 0; i < 8; i++) { sw += wred[i][0]; sb += wred[i][1]; }
    bwd_part[bid * 2 + 0] = sw;    // W1 trace partial
    bwd_part[bid * 2 + 1] = sb;    // b1 trace partial
    if (jt == 0) {
      float s2 = 0.f, sb2 = 0.f;
      #pragma unroll
      for (int i = 0; i < 8; i++) { s2 += hsqS[i] * tnormS[i]; sb2 += tnormS[i]; }
      samp_part[sg * 2 + 0] = s2;  // W2 trace partial
      samp_part[sg * 2 + 1] = sb2; // b2 trace partial
    }
    unsigned int old = __hip_atomic_fetch_add(counter, 1u, __ATOMIC_ACQ_REL,
                                              __HIP_MEMORY_SCOPE_AGENT);
    isLast = (old == 255u);
  }
  __syncthreads();
  if (isLast) {                    // uniform across block
    float w1v = (t < 256) ? bwd_part[t * 2 + 0] : 0.f;
    float b1v = (t < 256) ? bwd_part[t * 2 + 1] : 0.f;
    float w2v = (t < 16) ? samp_part[t * 2 + 0] : 0.f;
    float b2v = (t < 16) ? samp_part[t * 2 + 1] : 0.f;
    w1v = block_sum512(w1v, red);
    b1v = block_sum512(b1v, red);
    w2v = block_sum512(w2v, red);
    b2v = block_sum512(b2v, red);
    if (t == 0) {
      w1v /= 128.0f; b1v /= 128.0f; w2v /= 128.0f; b2v /= 128.0f;
      out[0] = w1v + b1v + w2v + b2v;
      out[1] = w1v;
      out[2] = b1v;
      out[3] = w2v;
      out[4] = b2v;
    }
  }
}

// ---------------------------------------------------------------------------
extern "C" void kernel_launch(void* const* d_in, const int* in_sizes, int n_in,
                              void* d_out, int out_size, void* d_ws, size_t ws_size,
                              hipStream_t stream) {
  const float* X  = (const float*)d_in[0];
  const float* W1 = (const float*)d_in[1];
  const float* b1 = (const float*)d_in[2];
  const float* W2 = (const float*)d_in[3];
  const float* b2 = (const float*)d_in[4];
  float* out = (float*)d_out;

  float* ws        = (float*)d_ws;
  float* hfinal    = ws;                          // 131072
  float* lpart     = hfinal + B_N * H_N;          // 16 * 131072 (8 MB)
  float* gtab      = lpart + NJT * LP_STRIDE;     // 131072
  float* xsq       = gtab + B_N * CP;             // 128
  float* samp_part = xsq + B_N;                   // 32
  float* bwd_part  = samp_part + 32;              // 512
  unsigned int* counter = (unsigned int*)(bwd_part + 512);

  k_fwd<<<256, 512, 0, stream>>>(X, W1, b1, W2, hfinal, lpart, gtab, xsq, counter);
  k_tail<<<256, 512, 0, stream>>>(lpart, b2, gtab, W2, hfinal, xsq,
                                  samp_part, bwd_part, counter, out);
}

// Round 11
// 62.364 us; speedup vs baseline: 1.3287x; 1.3287x over previous
//
#include <hip/hip_runtime.h>
#include <hip/hip_bf16.h>
#include <stdint.h>
#include <math.h>

#define B_N 128
#define D_N 512
#define H_N 1024
#define C_N 1000
#define CP  1024                 // padded row stride for logit partials / g
#define NJT 16                   // j-split planes (K=64 each) -- absmax-0-proven order
#define LP_STRIDE (B_N * CP)

// ---------------------------------------------------------------------------
// threefry2x32 (JAX-compatible, 20 rounds) -- verified bit-exact (R1 absmax 0)
// ---------------------------------------------------------------------------
__device__ __forceinline__ uint32_t rotl32(uint32_t v, int r) {
  return (v << r) | (v >> (32 - r));
}

__device__ __forceinline__ void threefry2x32(uint32_t k0, uint32_t k1,
                                             uint32_t x0, uint32_t x1,
                                             uint32_t &o0, uint32_t &o1) {
  uint32_t ks2 = k0 ^ k1 ^ 0x1BD11BDAu;
#define TF_R(r) { x0 += x1; x1 = rotl32(x1, r); x1 ^= x0; }
  x0 += k0; x1 += k1;
  TF_R(13) TF_R(15) TF_R(26) TF_R(6)
  x0 += k1; x1 += ks2 + 1u;
  TF_R(17) TF_R(29) TF_R(16) TF_R(24)
  x0 += ks2; x1 += k0 + 2u;
  TF_R(13) TF_R(15) TF_R(26) TF_R(6)
  x0 += k0; x1 += k1 + 3u;
  TF_R(17) TF_R(29) TF_R(16) TF_R(24)
  x0 += k1; x1 += ks2 + 4u;
  TF_R(13) TF_R(15) TF_R(26) TF_R(6)
  x0 += ks2; x1 += k0 + 5u;
#undef TF_R
  o0 = x0; o1 = x1;
}

__device__ __forceinline__ float gumbel_from_key(uint32_t k0, uint32_t k1, uint32_t i) {
  uint32_t o0, o1;
  threefry2x32(k0, k1, 0u, i, o0, o1);
  uint32_t bits = o0 ^ o1;
  uint32_t fb = (bits >> 9) | 0x3f800000u;
  float f = __uint_as_float(fb) - 1.0f;            // [0, 1)
  const float tiny = 1.1754943508222875e-38f;
  float u = fmaxf(tiny, f * (1.0f - tiny) + tiny); // JAX uniform(minval=tiny)
  return -logf(-logf(u));
}

// ---------------------------------------------------------------------------
__device__ __forceinline__ float wave_sum(float v) {
  #pragma unroll
  for (int o = 32; o; o >>= 1) v += __shfl_xor(v, o);
  return v;
}

__device__ __forceinline__ float block_sum512(float v, float* red) {
  #pragma unroll
  for (int o = 32; o; o >>= 1) v += __shfl_xor(v, o);
  __syncthreads();
  if ((threadIdx.x & 63) == 0) red[threadIdx.x >> 6] = v;
  __syncthreads();
  return red[0] + red[1] + red[2] + red[3] + red[4] + red[5] + red[6] + red[7];
}

__device__ __forceinline__ float block_max512(float v, float* red) {
  #pragma unroll
  for (int o = 32; o; o >>= 1) v = fmaxf(v, __shfl_xor(v, o));
  __syncthreads();
  if ((threadIdx.x & 63) == 0) red[threadIdx.x >> 6] = v;
  __syncthreads();
  float m = red[0];
  #pragma unroll
  for (int w = 1; w < 8; w++) m = fmaxf(m, red[w]);
  return m;
}

// ---------------------------------------------------------------------------
// NODE 1: fused fc1+fc2 per j-slab (R10-proven, absmax 0.0, sub-fill dur).
// grid 256 = sg(16: 8 samples) x jt(16: 64 j). XCD = bid%8 = jt%8 -> W1 slab
// (128 KB) + W2 slab (256 KB) L2-resident, shared by that XCD's 16+ blocks.
// Phase A: h[8s][64j] = X @ W1[:,slab] + b1 (K=512 ascending, bit-identical
//          to R9 fc1); write hfinal; relu -> LDS. xsq (jt==0); counter (bid 0).
// Phase B: lpart[jt] = relu(h) @ W2[slab,:], j ascending (bit-identical to
//          R9 fc2). Pads [1000,1024) unwritten; consumers guard c < C_N.
// ---------------------------------------------------------------------------
__global__ __launch_bounds__(512) void k_fwd(const float* __restrict__ X,
                                             const float* __restrict__ W1,
                                             const float* __restrict__ b1,
                                             const float* __restrict__ W2,
                                             float* __restrict__ hfinal,
                                             float* __restrict__ lpart,
                                             float* __restrict__ xsq,
                                             unsigned int* __restrict__ counter) {
  __shared__ float xs[8 * D_N];   // 16 KB [s][d]
  __shared__ float hT[64 * 9];    // [j][s], pad 9 to spread banks
  int bid = blockIdx.x;
  int sg = bid >> 4, jt = bid & 15;
  int sbase = sg * 8, jbase = jt * 64;
  int t = threadIdx.x;
  if (bid == 0 && t == 0) *counter = 0u;

  #pragma unroll
  for (int k = 0; k < 2; k++) {
    int i4 = t + k * 512;          // 0..1023 float4s = 8 rows x 128
    int s = i4 >> 7, dq = i4 & 127;
    *reinterpret_cast<float4*>(&xs[s * D_N + dq * 4]) =
        *reinterpret_cast<const float4*>(&X[(size_t)(sbase + s) * D_N + dq * 4]);
  }
  __syncthreads();

  // Phase A: fc1. thread = (s = t>>6, j = t&63); K = 512 ascending scalar adds.
  int s = t >> 6, j = t & 63;
  const float* W1c = W1 + jbase + j;
  const float* xp = &xs[s * D_N];
  float a0 = 0.f;
  float wA[8], wB[8];
  #pragma unroll
  for (int i = 0; i < 8; i++) wA[i] = W1c[(size_t)i * H_N];
  for (int d0 = 0; d0 < D_N; d0 += 16) {
    #pragma unroll
    for (int i = 0; i < 8; i++) wB[i] = W1c[(size_t)((d0 + 8 + i) & (D_N - 1)) * H_N];
    #pragma unroll
    for (int i = 0; i < 8; i++) a0 += wA[i] * xp[d0 + i];
    #pragma unroll
    for (int i = 0; i < 8; i++) wA[i] = W1c[(size_t)((d0 + 16 + i) & (D_N - 1)) * H_N];
    #pragma unroll
    for (int i = 0; i < 8; i++) a0 += wB[i] * xp[d0 + 8 + i];
  }
  float h = a0 + b1[jbase + j];
  hfinal[(size_t)(sbase + s) * H_N + jbase + j] = h;
  hT[j * 9 + s] = fmaxf(h, 0.f);

  if (jt == 0) {                   // xsq, same per-lane order as R9 (bit-exact)
    int lane = t & 63;
    float v = 0.f;
    #pragma unroll
    for (int k = 0; k < 8; k++) { float xv = xs[s * D_N + lane + k * 64]; v += xv * xv; }
    v = wave_sum(v);
    if (lane == 0) xsq[sbase + s] = v;
  }
  __syncthreads();

  // Phase B: fc2. thread = 2 c-cols (t, t+512) x 8 samples; j ascending 0..63.
  int c0 = t;
  bool c1ok = (t + 512) < C_N;
  float acc0[8] = {0,0,0,0,0,0,0,0};
  float acc1[8] = {0,0,0,0,0,0,0,0};
  const float* W2r = W2 + (size_t)jbase * C_N;
  #pragma unroll 8
  for (int jj = 0; jj < 64; jj++) {
    float w0 = W2r[(size_t)jj * C_N + c0];
    float w1 = c1ok ? W2r[(size_t)jj * C_N + c0 + 512] : 0.f;
    #pragma unroll
    for (int ss = 0; ss < 8; ss++) {
      float hv = hT[jj * 9 + ss];
      acc0[ss] += w0 * hv;
      acc1[ss] += w1 * hv;
    }
  }
  float* lp = lpart + (size_t)jt * LP_STRIDE;
  #pragma unroll
  for (int ss = 0; ss < 8; ss++) {
    lp[(size_t)(sbase + ss) * CP + c0] = acc0[ss];
    if (c1ok) lp[(size_t)(sbase + ss) * CP + c0 + 512] = acc1[ss];
  }
}

// ---------------------------------------------------------------------------
// NODE 2: sampler (R9-verbatim, absmax-0-proven). One block (512 thr) per
// sample: sum NJT planes + b2 ascending, gumbel-argmax, softmax grad g ->
// global (zero-padded), W2/b2 trace partials.
// ---------------------------------------------------------------------------
__global__ __launch_bounds__(512) void k_sample(const float* __restrict__ lpart,
                                                const float* __restrict__ b2,
                                                const float* __restrict__ hfinal,
                                                float* __restrict__ g,
                                                float* __restrict__ samp_part) {
  __shared__ float lg[C_N];
  __shared__ float red[8];
  __shared__ float redv[8];
  __shared__ int   redi[8];
  __shared__ uint32_t keys[2];
  int b = blockIdx.x;
  int t = threadIdx.x;
  {
    float sA = b2[t];
    float sB = (t + 512 < C_N) ? b2[t + 512] : 0.f;
    #pragma unroll
    for (int p = 0; p < NJT; p++) {
      const float* lp = lpart + (size_t)p * LP_STRIDE + (size_t)b * CP;
      sA += lp[t];
      if (t + 512 < C_N) sB += lp[t + 512];
    }
    lg[t] = sA;
    if (t + 512 < C_N) lg[t + 512] = sB;
  }
  if (t == 0) {
    uint32_t o0, o1;
    threefry2x32(0u, 42u, 0u, (uint32_t)b, o0, o1);
    keys[0] = o0; keys[1] = o1;
  }
  __syncthreads();
  uint32_t k0 = keys[0], k1 = keys[1];
  float bz = -INFINITY; int bi = 0x7fffffff;
  {
    float z0 = lg[t] + gumbel_from_key(k0, k1, (uint32_t)t);
    bz = z0; bi = t;
    if (t + 512 < C_N) {
      float z1 = lg[t + 512] + gumbel_from_key(k0, k1, (uint32_t)(t + 512));
      if (z1 > bz || (z1 == bz && (t + 512) < bi)) { bz = z1; bi = t + 512; }
    }
  }
  #pragma unroll
  for (int o = 32; o; o >>= 1) {
    float ov = __shfl_xor(bz, o);
    int   oi = __shfl_xor(bi, o);
    if (ov > bz || (ov == bz && oi < bi)) { bz = ov; bi = oi; }
  }
  if ((t & 63) == 0) { redv[t >> 6] = bz; redi[t >> 6] = bi; }
  __syncthreads();
  if (t == 0) {
    #pragma unroll
    for (int w = 1; w < 8; w++) {
      if (redv[w] > redv[0] || (redv[w] == redv[0] && redi[w] < redi[0])) {
        redv[0] = redv[w]; redi[0] = redi[w];
      }
    }
  }
  __syncthreads();
  int y = redi[0];
  float lm = lg[t];
  if (t + 512 < C_N) lm = fmaxf(lm, lg[t + 512]);
  float m = block_max512(lm, red);
  float ea = expf(lg[t] - m);
  float eb = (t + 512 < C_N) ? expf(lg[t + 512] - m) : 0.0f;
  float sum1 = block_sum512(ea + eb, red);
  float inv = 1.0f / sum1;
  float ga  = ea * inv - ((t == y) ? 1.0f : 0.0f);
  float gb2 = eb * inv - (((t + 512) == y) ? 1.0f : 0.0f);
  g[(size_t)b * CP + t] = ga;
  g[(size_t)b * CP + t + 512] = (t + 512 < C_N) ? gb2 : 0.0f;  // zero pads
  float gn = ga * ga + ((t + 512 < C_N) ? gb2 * gb2 : 0.0f);
  float tnorm = block_sum512(gn, red);   // ||g||^2

  float h0 = hfinal[(size_t)b * H_N + t];
  float h1 = hfinal[(size_t)b * H_N + t + 512];
  float r0 = fmaxf(h0, 0.f), r1 = fmaxf(h1, 0.f);
  float hsq = block_sum512(r0 * r0 + r1 * r1, red);

  if (t == 0) {
    samp_part[b * 2 + 0] = hsq * tnorm;  // W2 trace numerator
    samp_part[b * 2 + 1] = tnorm;        // b2 trace numerator
  }
}

// ---------------------------------------------------------------------------
// NODE 3: backward (R9-verbatim) + arrival-counter final reduce.
// grid 512 = sg(16) x jt(32: 32 j-rows); XCD = jt%8 -> 512 KB W2 per XCD.
// ---------------------------------------------------------------------------
__global__ __launch_bounds__(512) void k_bwd(const float* __restrict__ g,
                                             const float* __restrict__ W2,
                                             const float* __restrict__ hfinal,
                                             const float* __restrict__ xsq_g,
                                             const float* __restrict__ samp_part,
                                             float* __restrict__ bwd_part,
                                             unsigned int* __restrict__ counter,
                                             float* __restrict__ out) {
  __shared__ float gs[8 * 1024];  // 32 KB
  __shared__ float xq[8];
  __shared__ float wred[8][2];
  __shared__ float red[8];
  __shared__ int isLast;
  int bid = blockIdx.x;
  int jt = bid & 31, sg = bid >> 5;
  int sbase = sg * 8, jbase = jt * 32;
  int t = threadIdx.x, w = t >> 6, lane = t & 63;
  #pragma unroll
  for (int k = 0; k < 16; k++) {
    int idx = t + k * 512;            // 0..8191
    gs[idx] = g[(size_t)(sbase + (idx >> 10)) * CP + (idx & 1023)];
  }
  if (t < 8) xq[t] = xsq_g[sbase + t];
  __syncthreads();

  float cb = 0.f, cw = 0.f;
  #pragma unroll
  for (int it2 = 0; it2 < 2; it2++) {
    int jb = jbase + it2 * 16;
    int j0 = jb + w * 2, j1 = j0 + 1;
    float a0[8] = {0,0,0,0,0,0,0,0};
    float a1[8] = {0,0,0,0,0,0,0,0};
    const float* w2r0 = W2 + (size_t)j0 * C_N;
    const float* w2r1 = W2 + (size_t)j1 * C_N;
    #pragma unroll
    for (int it = 0; it < 4; it++) {
      int c0 = it * 256 + lane * 4;
      bool act = (c0 < C_N);
      float4 wv0 = act ? *reinterpret_cast<const float4*>(w2r0 + c0)
                       : make_float4(0.f, 0.f, 0.f, 0.f);
      float4 wv1 = act ? *reinterpret_cast<const float4*>(w2r1 + c0)
                       : make_float4(0.f, 0.f, 0.f, 0.f);
      #pragma unroll
      for (int s = 0; s < 8; s++) {
        float4 gv = *reinterpret_cast<const float4*>(&gs[s * 1024 + c0]);
        a0[s] += wv0.x * gv.x + wv0.y * gv.y + wv0.z * gv.z + wv0.w * gv.w;
        a1[s] += wv1.x * gv.x + wv1.y * gv.y + wv1.z * gv.z + wv1.w * gv.w;
      }
    }
    #pragma unroll
    for (int off = 32; off; off >>= 1) {
      #pragma unroll
      for (int s = 0; s < 8; s++) {
        a0[s] += __shfl_xor(a0[s], off);
        a1[s] += __shfl_xor(a1[s], off);
      }
    }
    #pragma unroll
    for (int s = 0; s < 8; s++) {
      float h0 = hfinal[(size_t)(sbase + s) * H_N + j0];
      float h1 = hfinal[(size_t)(sbase + s) * H_N + j1];
      float v0 = (h0 > 0.f) ? a0[s] : 0.f;
      float v1 = (h1 > 0.f) ? a1[s] : 0.f;
      float q = v0 * v0 + v1 * v1;
      cb += q;
      cw += xq[s] * q;
    }
  }
  if (lane == 0) { wred[w][0] = cw; wred[w][1] = cb; }
  __syncthreads();

  if (t == 0) {
    float sw = 0.f, sb = 0.f;
    #pragma unroll
    for (int i = 0; i < 8; i++) { sw += wred[i][0]; sb += wred[i][1]; }
    bwd_part[bid * 2 + 0] = sw;    // W1 trace partial
    bwd_part[bid * 2 + 1] = sb;    // b1 trace partial
    unsigned int old = __hip_atomic_fetch_add(counter, 1u, __ATOMIC_ACQ_REL,
                                              __HIP_MEMORY_SCOPE_AGENT);
    isLast = (old == 511u);
  }
  __syncthreads();
  if (isLast) {                    // uniform across block
    float w1v = bwd_part[t * 2 + 0];
    float b1v = bwd_part[t * 2 + 1];
    float w2v = (t < B_N) ? samp_part[t * 2 + 0] : 0.f;
    float b2v = (t < B_N) ? samp_part[t * 2 + 1] : 0.f;
    w1v = block_sum512(w1v, red);
    b1v = block_sum512(b1v, red);
    w2v = block_sum512(w2v, red);
    b2v = block_sum512(b2v, red);
    if (t == 0) {
      w1v /= 128.0f; b1v /= 128.0f; w2v /= 128.0f; b2v /= 128.0f;
      out[0] = w1v + b1v + w2v + b2v;
      out[1] = w1v;
      out[2] = b1v;
      out[3] = w2v;
      out[4] = b2v;
    }
  }
}

// ---------------------------------------------------------------------------
extern "C" void kernel_launch(void* const* d_in, const int* in_sizes, int n_in,
                              void* d_out, int out_size, void* d_ws, size_t ws_size,
                              hipStream_t stream) {
  const float* X  = (const float*)d_in[0];
  const float* W1 = (const float*)d_in[1];
  const float* b1 = (const float*)d_in[2];
  const float* W2 = (const float*)d_in[3];
  const float* b2 = (const float*)d_in[4];
  float* out = (float*)d_out;

  float* ws        = (float*)d_ws;
  float* hfinal    = ws;                          // 131072
  float* lpart     = hfinal + B_N * H_N;          // 16 * 131072 (8 MB)
  float* g         = lpart + NJT * LP_STRIDE;     // 131072
  float* xsq       = g + B_N * CP;                // 128
  float* samp_part = xsq + B_N;                   // 256
  float* bwd_part  = samp_part + 256;             // 1024
  unsigned int* counter = (unsigned int*)(bwd_part + 1024);

  k_fwd<<<256, 512, 0, stream>>>(X, W1, b1, W2, hfinal, lpart, xsq, counter);
  k_sample<<<B_N, 512, 0, stream>>>(lpart, b2, hfinal, g, samp_part);
  k_bwd<<<512, 512, 0, stream>>>(g, W2, hfinal, xsq, samp_part,
                                 bwd_part, counter, out);
}